// Round 11
// baseline (1519.469 us; speedup 1.0000x reference)
//
#include <hip/hip_runtime.h>

// RGCN on MI355X — round 18: r17 resubmit (container died twice, r13-style;
// r13->r14 precedent says infra). Full audit found no hang/OOB/divergent-
// barrier fault in fused_layer (all barriers uniform, all indices bounded,
// vmcnt(0)-only waits). Pre-commit: if this fails twice again, the kernel is
// implicated -> r19 reverts to the r16 materialized-T baseline.
// Design (aggregate-then-transform, kills the T tensor):
//   out[dst] = SUM_r (SUM_{e in(dst),et=r} norm*feat[src]) @ W[r]
// Per (32-dst tile, rel): contiguous CSR(et*N+dst) edge range -> batch-64
// payload + shfl -> per-edge LDS fp32 atomicAdd into aggF -> bf16 convert ->
// MFMA (asm-B regs, transposed) accumulating across rels in registers ->
// ONE store per block. T (205MB W + 205MB R) gone; feat/h (12.8MB) L2-hot.
// Fast path:
//   to_bf16: feat -> nbf; CSR(et*N+dst); h = relu(fused<128,0>) -> hbf;
//   out = fused<64,1> -> d_out.
// Fallback (small ws / huge N): chunked atomic path (unchanged).

#define R_NUM 16

typedef __attribute__((ext_vector_type(8))) short bf16x8;
typedef __attribute__((ext_vector_type(4))) float f32x4;

__device__ __forceinline__ float bf2f(unsigned short u) {
    unsigned int x = ((unsigned int)u) << 16;
    return __builtin_bit_cast(float, x);
}
__device__ __forceinline__ unsigned short f2bf(float f) {
    unsigned int x = __builtin_bit_cast(unsigned int, f);
    x += 0x7FFFu + ((x >> 16) & 1u);  // RNE
    return (unsigned short)(x >> 16);
}
__device__ __forceinline__ unsigned pack2(float a, float b) {
    return (unsigned)f2bf(a) | ((unsigned)f2bf(b) << 16);
}
__device__ __forceinline__ float lo16(unsigned v) { return bf2f((unsigned short)(v & 0xFFFF)); }
__device__ __forceinline__ float hi16(unsigned v) { return bf2f((unsigned short)(v >> 16)); }

// Raw 16B global load the compiler cannot sink/remat/delete (r12-proven).
__device__ __forceinline__ bf16x8 gload16(const unsigned short* p) {
    bf16x8 r;
    asm volatile("global_load_dwordx4 %0, %1, off" : "=&v"(r) : "v"(p));
    return r;
}

// ---------------- dtype sniffer (fp32 vs bf16 harness inputs) ----------------
__global__ void detect_dtype(const unsigned short* __restrict__ raw, int* flag) {
    __shared__ int tot;
    if (threadIdx.x == 0) tot = 0;
    __syncthreads();
    int c = 0;
    for (int i = threadIdx.x; i < 4096; i += 256) {
        unsigned short u = raw[2 * i];
        int e = (u >> 7) & 0xFF;
        if (e >= 113 && e <= 134) c++;
    }
    atomicAdd(&tot, c);
    __syncthreads();
    if (threadIdx.x == 0) *flag = (tot > 2048) ? 1 : 0;  // 1 => bf16 inputs
}

// Both weight transposes in one launch: W[r][k][o] -> Wt[r][o][k] bf16.
__global__ void transpose_both(const void* __restrict__ W1, const void* __restrict__ W2,
                               unsigned short* __restrict__ w1t, unsigned short* __restrict__ w2t,
                               const int* __restrict__ flagp) {
    const int flag = *flagp;
    const int n1 = R_NUM * 128 * 128;
    const int n2 = R_NUM * 128 * 64;
    int idx = blockIdx.x * 256 + threadIdx.x;
    if (idx < n1) {
        int k = idx % 128, o = (idx / 128) % 128, r = idx / (128 * 128);
        int iin = (r * 128 + k) * 128 + o;
        float v = flag ? bf2f(((const unsigned short*)W1)[iin]) : ((const float*)W1)[iin];
        w1t[idx] = f2bf(v);
    } else if (idx < n1 + n2) {
        int j = idx - n1;
        int k = j % 128, o = (j / 128) % 64, r = j / (128 * 64);
        int iin = (r * 128 + k) * 64 + o;
        float v = flag ? bf2f(((const unsigned short*)W2)[iin]) : ((const float*)W2)[iin];
        w2t[j] = f2bf(v);
    }
}

// Pack node features to bf16 once (n8 = nnodes*16 uint4 segments).
__global__ void to_bf16(const void* __restrict__ in, unsigned short* __restrict__ out, int n8,
                        const int* __restrict__ flagp) {
    int i = blockIdx.x * 256 + threadIdx.x;
    if (i >= n8) return;
    uint4 v;
    if (*flagp) {
        v = ((const uint4*)in)[i];
    } else {
        const float4* p = (const float4*)in + (size_t)i * 2;
        float4 f0 = p[0];
        float4 f1 = p[1];
        v.x = pack2(f0.x, f0.y);
        v.y = pack2(f0.z, f0.w);
        v.z = pack2(f1.x, f1.y);
        v.w = pack2(f1.z, f1.w);
    }
    ((uint4*)out)[i] = v;
}

// ---------------- CSR build over key = et*nnodes + dst ----------------
__global__ void hist_key(const int* __restrict__ dst, const int* __restrict__ et,
                         int* __restrict__ counts, int nedges, int nnodes) {
    int e = blockIdx.x * 256 + threadIdx.x;
    if (e < nedges) atomicAdd(&counts[et[e] * nnodes + dst[e]], 1);
}

__global__ __launch_bounds__(256) void scan_phase1(const int* __restrict__ counts,
                                                   int* __restrict__ blocksums, int n) {
    __shared__ int red[256];
    int base = blockIdx.x * 1024 + threadIdx.x * 4;
    int s = 0;
#pragma unroll
    for (int j = 0; j < 4; j++) {
        int idx = base + j;
        if (idx < n) s += counts[idx];
    }
    red[threadIdx.x] = s;
    __syncthreads();
    for (int d = 128; d > 0; d >>= 1) {
        if (threadIdx.x < d) red[threadIdx.x] += red[threadIdx.x + d];
        __syncthreads();
    }
    if (threadIdx.x == 0) blocksums[blockIdx.x] = red[0];
}

__global__ __launch_bounds__(1024) void scan_phase2(const int* __restrict__ blocksums,
                                                    int* __restrict__ blockoff, int nb) {
    __shared__ int arr[1024];
    int t = threadIdx.x;
    arr[t] = (t < nb) ? blocksums[t] : 0;
    __syncthreads();
    for (int d = 1; d < 1024; d <<= 1) {
        int v = (t >= d) ? arr[t - d] : 0;
        __syncthreads();
        arr[t] += v;
        __syncthreads();
    }
    if (t < nb) blockoff[t] = (t == 0) ? 0 : arr[t - 1];
}

__global__ __launch_bounds__(256) void scan_phase3(const int* __restrict__ counts,
                                                   const int* __restrict__ blockoff,
                                                   int* __restrict__ offsets,
                                                   int* __restrict__ cursor, int n) {
    __shared__ int tsum[256];
    int base = blockIdx.x * 1024 + threadIdx.x * 4;
    int c[4];
    int s = 0;
#pragma unroll
    for (int j = 0; j < 4; j++) {
        int idx = base + j;
        c[j] = (idx < n) ? counts[idx] : 0;
        s += c[j];
    }
    tsum[threadIdx.x] = s;
    __syncthreads();
    for (int d = 1; d < 256; d <<= 1) {
        int v = (threadIdx.x >= d) ? tsum[threadIdx.x - d] : 0;
        __syncthreads();
        tsum[threadIdx.x] += v;
        __syncthreads();
    }
    int run = blockoff[blockIdx.x] + ((threadIdx.x == 0) ? 0 : tsum[threadIdx.x - 1]);
#pragma unroll
    for (int j = 0; j < 4; j++) {
        int idx = base + j;
        if (idx < n) {
            offsets[idx] = run;
            cursor[idx] = run;
            if (idx == n - 1) offsets[n] = run + c[j];
            run += c[j];
        }
    }
}

// payload: pl.x = (dst&31)<<27 | src  (src < 2^27), pl.y = norm fp32
__global__ void fill_payload2(const int* __restrict__ src, const int* __restrict__ dst,
                              const int* __restrict__ et, const void* __restrict__ nrm,
                              const int* __restrict__ flagp, int* __restrict__ cursor,
                              uint2* __restrict__ payload, int nedges, int nnodes) {
    int e = blockIdx.x * 256 + threadIdx.x;
    if (e >= nedges) return;
    int flag = *flagp;
    float nm = flag ? bf2f(((const unsigned short*)nrm)[e]) : ((const float*)nrm)[e];
    int d = dst[e];
    int pos = atomicAdd(&cursor[et[e] * nnodes + d], 1);
    uint2 pl;
    pl.x = ((unsigned)(d & 31) << 27) | (unsigned)src[e];
    pl.y = __builtin_bit_cast(unsigned, nm);
    payload[pos] = pl;
}

// ---------------- fused layer: out[dst] = SUM_r agg_r(dst) @ W[r] ----------
// One block = 32 dst. Per rel: contiguous edge range [offs[r*N+node0],
// offs[r*N+node0+32]) -> batch-64 payload + shfl -> per-edge LDS atomicAdd
// into aggF[32][128] (edges independent) -> convert to bf16 aggB (+zero
// aggF) -> MFMA (transposed, asm-B in regs) accumulating acc across rels.
// Epilogue: one LDS C-transpose + one contiguous store.
// OUTMODE 0: relu+bf16 (h). OUTMODE 1: flag ? bf16 : fp32 (final output).
template <int NOUT, int OUTMODE>
__global__ __launch_bounds__(256, 3) void fused_layer(const unsigned* __restrict__ featU,
                                                      const unsigned short* __restrict__ Wt,
                                                      const int* __restrict__ offs,
                                                      const uint2* __restrict__ payload,
                                                      void* __restrict__ out, int nnodes,
                                                      const int* __restrict__ flagp) {
    constexpr int NTC = NOUT / 64;
    constexpr int AGF = 132;  // fp32 agg stride (floats)
    constexpr int ABS = 136;  // bf16 agg stride (shorts)
    __shared__ float aggF[32 * AGF];           // 16.9 KB
    __shared__ unsigned short aggB[32 * ABS];  // 8.7 KB
    const int tid = threadIdx.x;
    const int node0 = blockIdx.x * 32;
    const int w = tid >> 6, lane = tid & 63;
    const int quad = lane >> 4, mr = lane & 15;

    // wave-private B rows of Wt[r]: row w*16+mr (+c*64), 16B chunk per quad
    const unsigned short* wbase = Wt + ((size_t)(w * 16 + mr)) * 128 + quad * 8;
    bf16x8 bfr[2][NTC][4];
#pragma unroll
    for (int c = 0; c < NTC; c++)
#pragma unroll
        for (int kk = 0; kk < 4; kk++)
            bfr[0][c][kk] = gload16(wbase + (size_t)(c * 64) * 128 + kk * 32);

    for (int i = tid; i < 32 * AGF; i += 256) aggF[i] = 0.f;

    f32x4 acc[2][NTC];
#pragma unroll
    for (int mt = 0; mt < 2; mt++)
#pragma unroll
        for (int c = 0; c < NTC; c++) acc[mt][c] = 0.f;

    __syncthreads();

#pragma unroll 2
    for (int r = 0; r < R_NUM; r++) {
        // ---- aggregation: edges of (rel r, dst in [node0, node0+32)) ----
        const int kb = r * nnodes + node0;
        const int ke = r * nnodes + min(node0 + 32, nnodes);
        const int beg = offs[kb], end = offs[ke];
        const int m = end - beg;
        const int per = (m + 3) >> 2;
        const int cb = min(beg + w * per, end);
        const int ce = min(cb + per, end);
        for (int i = cb; i < ce; i += 64) {
            int cnt = min(64, ce - i);
            uint2 pl = make_uint2(0u, 0u);
            if (lane < cnt) pl = payload[i + lane];
            int j = 0;
            for (; j + 4 <= cnt; j += 4) {
                unsigned x0 = (unsigned)__shfl((int)pl.x, j);
                unsigned x1 = (unsigned)__shfl((int)pl.x, j + 1);
                unsigned x2 = (unsigned)__shfl((int)pl.x, j + 2);
                unsigned x3 = (unsigned)__shfl((int)pl.x, j + 3);
                float n0 = __builtin_bit_cast(float, (unsigned)__shfl((int)pl.y, j));
                float n1 = __builtin_bit_cast(float, (unsigned)__shfl((int)pl.y, j + 1));
                float n2 = __builtin_bit_cast(float, (unsigned)__shfl((int)pl.y, j + 2));
                float n3 = __builtin_bit_cast(float, (unsigned)__shfl((int)pl.y, j + 3));
                unsigned v0 = featU[(size_t)(x0 & 0x07FFFFFFu) * 64 + lane];
                unsigned v1 = featU[(size_t)(x1 & 0x07FFFFFFu) * 64 + lane];
                unsigned v2 = featU[(size_t)(x2 & 0x07FFFFFFu) * 64 + lane];
                unsigned v3 = featU[(size_t)(x3 & 0x07FFFFFFu) * 64 + lane];
                float* p0 = aggF + (x0 >> 27) * AGF + 2 * lane;
                float* p1 = aggF + (x1 >> 27) * AGF + 2 * lane;
                float* p2 = aggF + (x2 >> 27) * AGF + 2 * lane;
                float* p3 = aggF + (x3 >> 27) * AGF + 2 * lane;
                atomicAdd(p0, lo16(v0) * n0);
                atomicAdd(p0 + 1, hi16(v0) * n0);
                atomicAdd(p1, lo16(v1) * n1);
                atomicAdd(p1 + 1, hi16(v1) * n1);
                atomicAdd(p2, lo16(v2) * n2);
                atomicAdd(p2 + 1, hi16(v2) * n2);
                atomicAdd(p3, lo16(v3) * n3);
                atomicAdd(p3 + 1, hi16(v3) * n3);
            }
            for (; j < cnt; j++) {
                unsigned x = (unsigned)__shfl((int)pl.x, j);
                float nm = __builtin_bit_cast(float, (unsigned)__shfl((int)pl.y, j));
                unsigned v = featU[(size_t)(x & 0x07FFFFFFu) * 64 + lane];
                float* p = aggF + (x >> 27) * AGF + 2 * lane;
                atomicAdd(p, lo16(v) * nm);
                atomicAdd(p + 1, hi16(v) * nm);
            }
        }
        __syncthreads();  // agg visible block-wide (no global stores in flight)

        // ---- convert fp32 -> bf16 (and zero aggF for next rel) ----
        for (int i = tid; i < 32 * 32; i += 256) {  // 32 rows x 32 float4
            int row = i >> 5, c4 = i & 31;
            float4 f = *(float4*)(aggF + row * AGF + c4 * 4);
            *(float4*)(aggF + row * AGF + c4 * 4) = make_float4(0.f, 0.f, 0.f, 0.f);
            uint2 pv;
            pv.x = pack2(f.x, f.y);
            pv.y = pack2(f.z, f.w);
            *(uint2*)(aggB + row * ABS + c4 * 4) = pv;
        }
        __syncthreads();  // aggB ready, aggF zeroed

        // B[r] landed (rule 18); then issue B[r+1] so its latency overlaps
        // MFMA + the next aggregation phase.
        asm volatile("s_waitcnt vmcnt(0)" ::: "memory");
        __builtin_amdgcn_sched_barrier(0);
        if (r + 1 < R_NUM) {
#pragma unroll
            for (int c = 0; c < NTC; c++)
#pragma unroll
                for (int kk = 0; kk < 4; kk++)
                    bfr[(r + 1) & 1][c][kk] =
                        gload16(wbase + (size_t)((r + 1) * NOUT + c * 64) * 128 + kk * 32);
        }

        // ---- MFMA: acc += (aggB @ W[r])^T fragments ----
#pragma unroll
        for (int kk = 0; kk < 4; kk++) {
            bf16x8 a[2];
#pragma unroll
            for (int mt = 0; mt < 2; mt++)
                a[mt] = *(const bf16x8*)(aggB + (mt * 16 + mr) * ABS + kk * 32 + quad * 8);
#pragma unroll
            for (int c = 0; c < NTC; c++)
#pragma unroll
                for (int mt = 0; mt < 2; mt++)
                    acc[mt][c] = __builtin_amdgcn_mfma_f32_16x16x32_bf16(bfr[r & 1][c][kk], a[mt],
                                                                         acc[mt][c], 0, 0, 0);
        }
        __syncthreads();  // aggB reads done before next convert overwrites
    }

    // ---- epilogue: acc -> LDS transpose -> one contiguous store ----
    const int flag = (OUTMODE == 1) ? *flagp : 0;
    if (OUTMODE == 0 || flag) {
        constexpr int LDC = NOUT + 8;
#pragma unroll
        for (int mt = 0; mt < 2; mt++)
#pragma unroll
            for (int c = 0; c < NTC; c++) {
                float x0 = acc[mt][c][0], x1 = acc[mt][c][1];
                float x2 = acc[mt][c][2], x3 = acc[mt][c][3];
                if (OUTMODE == 0) {
                    x0 = fmaxf(x0, 0.f);
                    x1 = fmaxf(x1, 0.f);
                    x2 = fmaxf(x2, 0.f);
                    x3 = fmaxf(x3, 0.f);
                }
                uint2 pv;
                pv.x = pack2(x0, x1);
                pv.y = pack2(x2, x3);
                *(uint2*)(aggB + (mt * 16 + mr) * LDC + c * 64 + w * 16 + quad * 4) = pv;
            }
        __syncthreads();
        constexpr int SEGS = NOUT / 8;
        for (int i = tid; i < 32 * SEGS; i += 256) {
            int row = i / SEGS, seg = i % SEGS;
            int node = node0 + row;
            if (node < nnodes)
                *(uint4*)((unsigned short*)out + (size_t)node * NOUT + seg * 8) =
                    *(const uint4*)(aggB + row * LDC + seg * 8);
        }
    } else {
        constexpr int LDCF = NOUT + 4;
#pragma unroll
        for (int mt = 0; mt < 2; mt++)
#pragma unroll
            for (int c = 0; c < NTC; c++) {
                *(float4*)(aggF + (mt * 16 + mr) * LDCF + c * 64 + w * 16 + quad * 4) =
                    make_float4(acc[mt][c][0], acc[mt][c][1], acc[mt][c][2], acc[mt][c][3]);
            }
        __syncthreads();
        constexpr int SEGF = NOUT / 4;
        for (int i = tid; i < 32 * SEGF; i += 256) {
            int row = i / SEGF, seg = i % SEGF;
            int node = node0 + row;
            if (node < nnodes)
                *(float4*)((float*)out + (size_t)node * NOUT + seg * 4) =
                    *(const float4*)(aggF + row * LDCF + seg * 4);
        }
    }
}

// ---------------- fallback path (chunked + atomics, node-major t) ----------------
template <int NOUT, int AMODE>
__global__ __launch_bounds__(256) void gemm_rel(const void* __restrict__ Asrc,
                                                const unsigned short* __restrict__ Wt,
                                                unsigned short* __restrict__ T, int nnodes,
                                                int rbase, const int* __restrict__ flagp) {
    constexpr int LDA = 136;
    __shared__ unsigned short lA[64 * LDA];
    __shared__ unsigned short lB[NOUT * LDA];
    const int tid = threadIdx.x;
    const int node0 = blockIdx.x * 64;
    const int rel = rbase + blockIdx.y;
    const int Gr = gridDim.y;
    const int flag = (AMODE == 0) ? *flagp : 1;

    for (int i = tid; i < 64 * 16; i += 256) {
        int row = i >> 4, seg = i & 15;
        int node = node0 + row;
        uint4 v = make_uint4(0u, 0u, 0u, 0u);
        if (node < nnodes) {
            if (AMODE == 1) {
                const float* p = (const float*)Asrc + (size_t)node * 128 + seg * 8;
                float4 f0 = ((const float4*)p)[0];
                float4 f1 = ((const float4*)p)[1];
                v.x = pack2(fmaxf(f0.x, 0.f), fmaxf(f0.y, 0.f));
                v.y = pack2(fmaxf(f0.z, 0.f), fmaxf(f0.w, 0.f));
                v.z = pack2(fmaxf(f1.x, 0.f), fmaxf(f1.y, 0.f));
                v.w = pack2(fmaxf(f1.z, 0.f), fmaxf(f1.w, 0.f));
            } else if (flag) {
                v = *(const uint4*)((const unsigned short*)Asrc + (size_t)node * 128 + seg * 8);
            } else {
                const float* p = (const float*)Asrc + (size_t)node * 128 + seg * 8;
                float4 f0 = ((const float4*)p)[0];
                float4 f1 = ((const float4*)p)[1];
                v.x = pack2(f0.x, f0.y);
                v.y = pack2(f0.z, f0.w);
                v.z = pack2(f1.x, f1.y);
                v.w = pack2(f1.z, f1.w);
            }
        }
        *(uint4*)(lA + row * LDA + seg * 8) = v;
    }
    for (int i = tid; i < NOUT * 16; i += 256) {
        int o = i >> 4, seg = i & 15;
        *(uint4*)(lB + o * LDA + seg * 8) =
            *(const uint4*)(Wt + ((size_t)rel * NOUT + o) * 128 + seg * 8);
    }
    __syncthreads();

    const int w = tid >> 6, lane = tid & 63;
    const int quad = lane >> 4, mr = lane & 15;
    constexpr int NT = NOUT / 16;
    f32x4 acc[NT];
#pragma unroll
    for (int t = 0; t < NT; t++) acc[t] = 0.f;
    const unsigned short* pa = lA + (w * 16 + mr) * LDA + quad * 8;
    const unsigned short* pb = lB + mr * LDA + quad * 8;
#pragma unroll
    for (int kk = 0; kk < 4; kk++) {
        bf16x8 a = *(const bf16x8*)(pa + kk * 32);
#pragma unroll
        for (int nt = 0; nt < NT; nt++) {
            bf16x8 b = *(const bf16x8*)(pb + nt * 16 * LDA + kk * 32);
            acc[nt] = __builtin_amdgcn_mfma_f32_16x16x32_bf16(a, b, acc[nt], 0, 0, 0);
        }
    }
#pragma unroll
    for (int nt = 0; nt < NT; nt++)
#pragma unroll
        for (int reg = 0; reg < 4; reg++) {
            int node = node0 + w * 16 + quad * 4 + reg;
            if (node < nnodes)
                T[((size_t)node * Gr + blockIdx.y) * NOUT + nt * 16 + mr] = f2bf(acc[nt][reg]);
        }
}

template <int NOUT>
__global__ void scatter_k(const unsigned short* __restrict__ T, int Gr, int rbase,
                          const void* __restrict__ nrm, const int* __restrict__ flagp,
                          const int* __restrict__ src, const int* __restrict__ dst,
                          const int* __restrict__ et, float* __restrict__ accum, int nedges) {
    constexpr int LPE = NOUT / 2;
    const int flag = *flagp;
    const int epb = 256 / LPE;
    const int sub = threadIdx.x % LPE;
    const int slot = threadIdx.x / LPE;
    for (int e = blockIdx.x * epb + slot; e < nedges; e += gridDim.x * epb) {
        int g = et[e] - rbase;
        if (g < 0 || g >= Gr) continue;
        int s = src[e], d = dst[e];
        float nm = flag ? bf2f(((const unsigned short*)nrm)[e]) : ((const float*)nrm)[e];
        unsigned pv = ((const unsigned*)(T + ((size_t)s * Gr + g) * NOUT))[sub];
        float* p = accum + (size_t)d * NOUT + sub * 2;
        unsafeAtomicAdd(p, lo16(pv) * nm);
        unsafeAtomicAdd(p + 1, hi16(pv) * nm);
    }
}

__global__ void write_out(const float* __restrict__ acc, void* __restrict__ dout, int n,
                          const int* __restrict__ flagp) {
    int flag = *flagp;
    int i = blockIdx.x * 256 + threadIdx.x;
    if (i >= n) return;
    float v = acc[i];
    if (flag) ((unsigned short*)dout)[i] = f2bf(v);
    else      ((float*)dout)[i] = v;
}

extern "C" void kernel_launch(void* const* d_in, const int* in_sizes, int n_in,
                              void* d_out, int out_size, void* d_ws, size_t ws_size,
                              hipStream_t stream) {
    const void* feat = d_in[0];
    const void* norm = d_in[1];
    const void* W1 = d_in[2];
    const void* W2 = d_in[3];
    const int* src = (const int*)d_in[4];
    const int* dst = (const int*)d_in[5];
    const int* et  = (const int*)d_in[6];

    const int nnodes = in_sizes[0] / 128;
    const int nedges = in_sizes[1];

    char* ws = (char*)d_ws;
    size_t off = 0;
    auto alloc = [&](size_t bytes) { size_t o = off; off += (bytes + 255) & ~255ULL; return o; };
    size_t off_flag = alloc(4);
    size_t off_w1t  = alloc((size_t)R_NUM * 128 * 128 * 2);
    size_t off_w2t  = alloc((size_t)R_NUM * 64 * 128 * 2);

    int* flagp = (int*)(ws + off_flag);
    unsigned short* w1t = (unsigned short*)(ws + off_w1t);
    unsigned short* w2t = (unsigned short*)(ws + off_w2t);

    const size_t nkeys = (size_t)R_NUM * nnodes;

    // fast-path layout
    size_t f_off = off;
    auto falloc = [&](size_t bytes) { size_t o = f_off; f_off += (bytes + 255) & ~255ULL; return o; };
    size_t off_offs = falloc((nkeys + 1) * 4);
    size_t off_curs = falloc(nkeys * 4);
    size_t off_cnt  = falloc(nkeys * 4);
    size_t off_bsum = falloc(1024 * 4);
    size_t off_boff = falloc(1024 * 4);
    size_t off_pay  = falloc((size_t)nedges * 8);
    size_t off_nbf  = falloc((size_t)nnodes * 128 * 2);  // feat bf16
    size_t off_hbf  = falloc((size_t)nnodes * 128 * 2);  // h bf16
    const int nb = (int)((nkeys + 1023) / 1024);
    bool fast = (f_off <= ws_size) && (nb <= 1024) && (nnodes <= 65536);

    const int ntr = R_NUM * 128 * 128 + R_NUM * 128 * 64;

    detect_dtype<<<1, 256, 0, stream>>>((const unsigned short*)feat, flagp);
    transpose_both<<<(ntr + 255) / 256, 256, 0, stream>>>(W1, W2, w1t, w2t, flagp);

    if (fast) {
        int* offs = (int*)(ws + off_offs);
        int* curs = (int*)(ws + off_curs);
        int* cnt  = (int*)(ws + off_cnt);
        int* bsum = (int*)(ws + off_bsum);
        int* boff = (int*)(ws + off_boff);
        uint2* pay = (uint2*)(ws + off_pay);
        unsigned short* nbf = (unsigned short*)(ws + off_nbf);
        unsigned short* hbf = (unsigned short*)(ws + off_hbf);

        hipMemsetAsync(cnt, 0, nkeys * 4, stream);
        hist_key<<<(nedges + 255) / 256, 256, 0, stream>>>(dst, et, cnt, nedges, nnodes);
        scan_phase1<<<nb, 256, 0, stream>>>(cnt, bsum, (int)nkeys);
        scan_phase2<<<1, 1024, 0, stream>>>(bsum, boff, nb);
        scan_phase3<<<nb, 256, 0, stream>>>(cnt, boff, offs, curs, (int)nkeys);
        fill_payload2<<<(nedges + 255) / 256, 256, 0, stream>>>(src, dst, et, norm, flagp,
                                                                curs, pay, nedges, nnodes);

        const int n8 = nnodes * 16;
        to_bf16<<<(n8 + 255) / 256, 256, 0, stream>>>(feat, nbf, n8, flagp);

        const int gxf = (nnodes + 31) / 32;
        fused_layer<128, 0><<<gxf, 256, 0, stream>>>((const unsigned*)nbf, w1t, offs, pay, hbf,
                                                     nnodes, flagp);
        fused_layer<64, 1><<<gxf, 256, 0, stream>>>((const unsigned*)hbf, w2t, offs, pay, d_out,
                                                    nnodes, flagp);
        return;
    }

    // fallback: chunked atomic path
    size_t off_hpre = alloc((size_t)nnodes * 128 * 4);
    size_t off_oacc = alloc((size_t)nnodes * 64 * 4);
    size_t t_cap = (ws_size > off) ? (ws_size - off) : 0;
    auto pick_gr = [&](int ncol) {
        int gr = 0;
        for (int g = 16; g >= 1; g >>= 1)
            if ((size_t)nnodes * g * ncol * 2 <= t_cap) { gr = g; break; }
        return gr;
    };
    int Gr1 = pick_gr(128);
    int Gr2 = pick_gr(64);
    if (Gr1 < 1 || Gr2 < 1) {
        hipMemsetAsync(d_out, 0x42, (size_t)out_size * 2, stream);
        return;
    }
    float* hpre = (float*)(ws + off_hpre);
    float* oacc = (float*)(ws + off_oacc);
    unsigned short* t = (unsigned short*)(ws + off);
    const int gx = (nnodes + 63) / 64;

    hipMemsetAsync(hpre, 0, (size_t)nnodes * 128 * 4, stream);
    hipMemsetAsync(oacc, 0, (size_t)nnodes * 64 * 4, stream);
    for (int rb = 0; rb < R_NUM; rb += Gr1) {
        gemm_rel<128, 0><<<dim3(gx, Gr1), 256, 0, stream>>>(feat, w1t, t, nnodes, rb, flagp);
        scatter_k<128><<<4096, 256, 0, stream>>>(t, Gr1, rb, norm, flagp, src, dst, et, hpre, nedges);
    }
    for (int rb = 0; rb < R_NUM; rb += Gr2) {
        gemm_rel<64, 1><<<dim3(gx, Gr2), 256, 0, stream>>>(hpre, w2t, t, nnodes, rb, flagp);
        scatter_k<64><<<4096, 256, 0, stream>>>(t, Gr2, rb, norm, flagp, src, dst, et, oacc, nedges);
    }
    int nout = nnodes * 64;
    write_out<<<(nout + 255) / 256, 256, 0, stream>>>(oacc, d_out, nout, flagp);
}